// Round 1
// baseline (233.005 us; speedup 1.0000x reference)
//
#include <hip/hip_runtime.h>

// TSAdaptivePatcher: x[64][64][8192] f32, mask[64][8192] i32
// PATCH=STRIDE=16 -> n_patches=512, non-overlapping => pure (c,p)-chunk transpose
// out = [ patches: 64*512*1024 f32 ][ padding_mask: 64*512 f32 ]
//
// v2: 64 KiB XOR-swizzled LDS tile (all 64 c x 16 patches), 512 threads.
//  Phase 1 (global->LDS): each wave reads ONE FULL 1 KiB contiguous c-row
//    per instruction (vs 512 B in v1) -> longer HBM bursts on the gather side.
//  Phase 2 (LDS->global): 16 output rows x 4 KiB fully contiguous stores.
//  LDS swizzle: float4-chunk index f stored at f ^ (c & 7). No pad -> tile is
//    exactly 65536 B (2 blocks/CU, 16 waves/CU, same occupancy as v1).
//    Both phases hit each 4-bank group exactly 8x per b128 instr = the
//    inherent 1KiB/128B minimum (no excess conflicts).

typedef float f4 __attribute__((ext_vector_type(4)));

constexpr int Bb  = 64;
constexpr int Cc  = 64;
constexpr int Ss  = 8192;
constexpr int NP  = 512;     // 1 + (8192-16)/16
constexpr int PT  = 16;      // patches per tile
constexpr size_t PATCH_ELEMS = (size_t)Bb * NP * Cc * 16; // 33,554,432

__global__ __launch_bounds__(512) void ts_patcher_kernel(
    const float* __restrict__ x,
    const int*   __restrict__ mask,
    float*       __restrict__ out)
{
    __shared__ f4 lds[Cc * 64];   // 64 rows x 64 float4 chunks = 65536 B exactly

    const int t   = threadIdx.x;
    const int blk = blockIdx.x;
    const int b   = blk >> 5;             // / (NP/PT) = /32
    const int P0  = (blk & 31) * PT;      // first patch of tile

    const float* xb = x + (size_t)b * Cc * Ss + (size_t)P0 * 16;

    // ---- Phase 1: global -> LDS ----
    // iter i covers c-rows [i*8, i*8+8); wave w reads row i*8+w as one
    // contiguous 1 KiB global_load (64 lanes x float4).
    {
        const int w = t >> 6;             // wave id 0..7
        const int l = t & 63;             // float4 chunk within the row
#pragma unroll
        for (int i = 0; i < 8; ++i) {
            const int c = i * 8 + w;
            const f4 v = *(const f4*)(xb + (size_t)c * Ss + l * 4);
            lds[c * 64 + (l ^ (c & 7))] = v;   // XOR bank-rotation swizzle
        }
    }

    __syncthreads();

    // ---- Phase 2: LDS -> global (16 contiguous 4 KiB output rows = 64 KiB) ----
    // iter i writes output rows (b, P0 + i*2 + pl); thread t covers floats
    // [tt*4, tt*4+4) of its row -> 1 KiB contiguous store per wave-instr.
    {
        float* otile = out + ((size_t)(b * NP + P0) * (Cc * 16));
        const int pl = t >> 8;            // 0..1: which of the 2 rows this iter
        const int tt = t & 255;           // float4 chunk within the 4 KiB row
        const int c  = tt >> 2;           // 0..63
        const int jj = tt & 3;            // float4 within the 16-float chunk
#pragma unroll
        for (int i = 0; i < 8; ++i) {
            const int p = i * 2 + pl;     // tile-local patch 0..15
            const f4 v = lds[c * 64 + ((p * 4 + jj) ^ (c & 7))];
            *(f4*)(otile + (size_t)p * 1024 + (size_t)tt * 4) = v;
        }
    }

    // ---- Fused padding mask: threads 0..15, one patch each ----
    if (t < PT) {
        const int p = P0 + t;
        const int4* m = (const int4*)(mask + (size_t)b * Ss + (size_t)p * 16);
        int4 a = m[0], d = m[1], e = m[2], f = m[3];
        int s = a.x + a.y + a.z + a.w
              + d.x + d.y + d.z + d.w
              + e.x + e.y + e.z + e.w
              + f.x + f.y + f.z + f.w;
        // mean >= 0.5  <=>  sum >= 8  (mask values in {0,1})
        out[PATCH_ELEMS + (size_t)b * NP + p] = (s >= 8) ? 1.0f : 0.0f;
    }
}

extern "C" void kernel_launch(void* const* d_in, const int* in_sizes, int n_in,
                              void* d_out, int out_size, void* d_ws, size_t ws_size,
                              hipStream_t stream) {
    const float* x    = (const float*)d_in[0];
    const int*   mask = (const int*)d_in[1];
    float*       out  = (float*)d_out;

    const int blocks = Bb * (NP / PT);   // 64 * 32 = 2048
    ts_patcher_kernel<<<blocks, 512, 0, stream>>>(x, mask, out);
}